// Round 1
// baseline (282.823 us; speedup 1.0000x reference)
//
#include <hip/hip_runtime.h>
#include <math.h>

#define NTOK 16384
#define DIM 2048
#define NEXP 64
#define BT 64              // tokens per block
#define KC 32              // k per stage
#define NSTAGE (DIM / KC)  // 64

// flat output offsets (return order)
#define OFF_W    0
#define OFF_I    32768
#define OFF_P    65536
#define OFF_ENT  1114112
#define OFF_CONF 1114113
#define OFF_UTIL 1114114

// zero the 66 stat slots (they are accumulated atomically by the main kernel)
__global__ void router_init(float* __restrict__ out) {
    int tid = threadIdx.x;
    if (tid < 66) out[OFF_ENT + tid] = 0.0f;
}

__global__ __launch_bounds__(256) void router_main(
    const float* __restrict__ x, const float* __restrict__ Wg,
    float* __restrict__ out)
{
    // xs: [k][token] transposed, pitch 68 so float4-over-token reads are 16B aligned
    __shared__ float xs[2][KC][BT + 4];
    // ws: [expert][k], pitch 36
    __shared__ float wsh[2][NEXP][KC + 4];
    // logits [token][expert] pitch 65 (2-way bank aliasing = free)
    __shared__ float lg[BT][NEXP + 1];
    __shared__ float m1s[BT], rss[BT];
    __shared__ float s_ent, s_conf, s_cnt[NEXP];

    const int tid = threadIdx.x;
    const int r = tid >> 4;   // 0..15 -> tokens 4r..4r+3
    const int c = tid & 15;   // 0..15 -> experts c, c+16, c+32, c+48
    const int t0 = blockIdx.x * BT;

    if (tid == 0) { s_ent = 0.0f; s_conf = 0.0f; }
    if (tid < NEXP) s_cnt[tid] = 0.0f;

    // staging assignment: quad Q = tid covers (row tk, quad q); Q = tid+256 covers row tk+32
    const int tk = tid >> 3;  // 0..31
    const int q  = tid & 7;   // 0..7

    const float* xg0 = x  + (size_t)(t0 + tk) * DIM + 4 * q;
    const float* xg1 = xg0 + (size_t)32 * DIM;
    const float* wg0 = Wg + (size_t)tk * DIM + 4 * q;
    const float* wg1 = wg0 + (size_t)32 * DIM;

    // prologue: stage 0
    float4 xa = *(const float4*)(xg0);
    float4 xb = *(const float4*)(xg1);
    float4 wa = *(const float4*)(wg0);
    float4 wb = *(const float4*)(wg1);
    xs[0][4*q+0][tk]      = xa.x; xs[0][4*q+1][tk]      = xa.y;
    xs[0][4*q+2][tk]      = xa.z; xs[0][4*q+3][tk]      = xa.w;
    xs[0][4*q+0][tk+32]   = xb.x; xs[0][4*q+1][tk+32]   = xb.y;
    xs[0][4*q+2][tk+32]   = xb.z; xs[0][4*q+3][tk+32]   = xb.w;
    *(float4*)&wsh[0][tk][4*q]      = wa;
    *(float4*)&wsh[0][tk+32][4*q]   = wb;
    __syncthreads();

    float acc[4][4];
    #pragma unroll
    for (int i = 0; i < 4; ++i)
        #pragma unroll
        for (int j = 0; j < 4; ++j) acc[i][j] = 0.0f;

    for (int s = 0; s < NSTAGE; ++s) {
        const int b = s & 1;
        if (s + 1 < NSTAGE) {
            const int kn = (s + 1) * KC;
            xa = *(const float4*)(xg0 + kn);
            xb = *(const float4*)(xg1 + kn);
            wa = *(const float4*)(wg0 + kn);
            wb = *(const float4*)(wg1 + kn);
        }
        #pragma unroll
        for (int k0 = 0; k0 < KC; k0 += 4) {
            float4 xv[4], wv[4];
            xv[0] = *(const float4*)&xs[b][k0+0][4*r];
            xv[1] = *(const float4*)&xs[b][k0+1][4*r];
            xv[2] = *(const float4*)&xs[b][k0+2][4*r];
            xv[3] = *(const float4*)&xs[b][k0+3][4*r];
            wv[0] = *(const float4*)&wsh[b][c     ][k0];
            wv[1] = *(const float4*)&wsh[b][c + 16][k0];
            wv[2] = *(const float4*)&wsh[b][c + 32][k0];
            wv[3] = *(const float4*)&wsh[b][c + 48][k0];
            const float* xp = (const float*)xv;  // xp[kk*4 + i]
            const float* wp = (const float*)wv;  // wp[j*4 + kk]
            #pragma unroll
            for (int kk = 0; kk < 4; ++kk)
                #pragma unroll
                for (int i = 0; i < 4; ++i)
                    #pragma unroll
                    for (int j = 0; j < 4; ++j)
                        acc[i][j] = fmaf(xp[kk*4 + i], wp[j*4 + kk], acc[i][j]);
        }
        if (s + 1 < NSTAGE) {
            const int nb = b ^ 1;
            xs[nb][4*q+0][tk]    = xa.x; xs[nb][4*q+1][tk]    = xa.y;
            xs[nb][4*q+2][tk]    = xa.z; xs[nb][4*q+3][tk]    = xa.w;
            xs[nb][4*q+0][tk+32] = xb.x; xs[nb][4*q+1][tk+32] = xb.y;
            xs[nb][4*q+2][tk+32] = xb.z; xs[nb][4*q+3][tk+32] = xb.w;
            *(float4*)&wsh[nb][tk][4*q]    = wa;
            *(float4*)&wsh[nb][tk+32][4*q] = wb;
        }
        __syncthreads();
    }

    // scatter logits to LDS
    #pragma unroll
    for (int i = 0; i < 4; ++i)
        #pragma unroll
        for (int j = 0; j < 4; ++j)
            lg[4*r + i][c + 16*j] = acc[i][j];
    __syncthreads();

    // one wave: top-2 + softmax stats per token
    if (tid < BT) {
        const int t = tid;
        float m1 = -INFINITY, m2 = -INFINITY;
        int i1 = 0, i2 = 0;
        for (int e = 0; e < NEXP; ++e) {
            float l = lg[t][e];
            if (l > m1)      { m2 = m1; i2 = i1; m1 = l; i1 = e; }
            else if (l > m2) { m2 = l; i2 = e; }
        }
        float ssum = 0.0f, tsum = 0.0f;
        for (int e = 0; e < NEXP; ++e) {
            float d = lg[t][e] - m1;
            float ex = __expf(d);
            ssum += ex;
            tsum += d * ex;
        }
        float rs = 1.0f / ssum;
        // H = -sum p log p  with  log p = d - ln(s):  H = ln(s) - (sum d e^d)/s
        float H  = logf(ssum) - tsum * rs;
        float e2 = __expf(m2 - m1);
        float rn = 1.0f / (1.0f + e2);
        float w0 = rn, w1v = e2 * rn;
        m1s[t] = m1; rss[t] = rs;

        *(float2*)&out[OFF_W + 2*(t0 + t)] = make_float2(w0, w1v);
        *(float2*)&out[OFF_I + 2*(t0 + t)] = make_float2((float)i1, (float)i2);

        atomicAdd(&s_ent,  H);
        atomicAdd(&s_conf, w0);
        atomicAdd(&s_cnt[i1], 1.0f);
        atomicAdd(&s_cnt[i2], 1.0f);
    }
    __syncthreads();

    // cooperative, coalesced probs write: 1024 float4s / 256 threads
    #pragma unroll
    for (int p = 0; p < 4; ++p) {
        int Q  = tid + 256 * p;
        int t  = Q >> 4;
        int qq = Q & 15;
        float m  = m1s[t];
        float rs = rss[t];
        float4 pr;
        pr.x = __expf(lg[t][4*qq + 0] - m) * rs;
        pr.y = __expf(lg[t][4*qq + 1] - m) * rs;
        pr.z = __expf(lg[t][4*qq + 2] - m) * rs;
        pr.w = __expf(lg[t][4*qq + 3] - m) * rs;
        *(float4*)&out[OFF_P + (size_t)(t0 + t) * NEXP + 4*qq] = pr;
    }

    // stats: pre-scaled so the atomic sums are exact (powers of two) / final means
    if (tid == 0) {
        atomicAdd(&out[OFF_ENT],  s_ent  * (1.0f / 16384.0f));
        atomicAdd(&out[OFF_CONF], s_conf * (1.0f / 16384.0f));
    }
    if (tid < NEXP)
        atomicAdd(&out[OFF_UTIL + tid], s_cnt[tid] * (1.0f / 32768.0f));
}

extern "C" void kernel_launch(void* const* d_in, const int* in_sizes, int n_in,
                              void* d_out, int out_size, void* d_ws, size_t ws_size,
                              hipStream_t stream) {
    const float* x  = (const float*)d_in[0];
    const float* Wg = (const float*)d_in[1];
    float* out = (float*)d_out;
    (void)d_ws; (void)ws_size; (void)in_sizes; (void)n_in; (void)out_size;

    router_init<<<dim3(1), dim3(128), 0, stream>>>(out);
    router_main<<<dim3(NTOK / BT), dim3(256), 0, stream>>>(x, Wg, out);
}